// Round 1
// baseline (907.307 us; speedup 1.0000x reference)
//
#include <hip/hip_runtime.h>
#include <stdint.h>

#define B_ROWS 8192
#define IN_DIM 4096
#define OUT_DIM 4096
#define KWORDS 128        // IN_DIM / 32 sign bits per word
#define KW4 32            // uint4 groups per row = KWORDS/4
#define BN_EPS 1e-5f

#define TILE 128
#define KC4 8             // uint4 (4-word) groups per row per k-chunk (32 words)
#define NCHUNK 4          // KWORDS / 32

// ---------------------------------------------------------------------------
// Pack fp32 signs into bit-words via wave ballot. Each wave handles 256
// contiguous floats (64 lanes x float4) -> 8 output words. The bit<->element
// permutation inside each 256-block is identical for x and w, and the
// XOR+popcount dot is invariant under any consistent permutation of the IN
// axis, so coalesced ballot packing is safe. 4096 % 256 == 0, so no block
// straddles a row boundary.
// ---------------------------------------------------------------------------
__global__ void pack_signs(const float* __restrict__ in, uint32_t* __restrict__ out) {
    int gid = blockIdx.x * blockDim.x + threadIdx.x;     // float4 index
    float4 v = reinterpret_cast<const float4*>(in)[gid];
    int lane = threadIdx.x & 63;
    int grp = gid >> 6;                                  // 256-element group id
    uint32_t s0 = __float_as_uint(v.x) >> 31;
    uint32_t s1 = __float_as_uint(v.y) >> 31;
    uint32_t s2 = __float_as_uint(v.z) >> 31;
    uint32_t s3 = __float_as_uint(v.w) >> 31;
    unsigned long long m;
    m = __ballot(s0);
    if (lane == 0)  out[grp * 8 + 0] = (uint32_t)m;
    if (lane == 32) out[grp * 8 + 1] = (uint32_t)(m >> 32);
    m = __ballot(s1);
    if (lane == 0)  out[grp * 8 + 2] = (uint32_t)m;
    if (lane == 32) out[grp * 8 + 3] = (uint32_t)(m >> 32);
    m = __ballot(s2);
    if (lane == 0)  out[grp * 8 + 4] = (uint32_t)m;
    if (lane == 32) out[grp * 8 + 5] = (uint32_t)(m >> 32);
    m = __ballot(s3);
    if (lane == 0)  out[grp * 8 + 6] = (uint32_t)m;
    if (lane == 32) out[grp * 8 + 7] = (uint32_t)(m >> 32);
}

// ---------------------------------------------------------------------------
// Binary GEMM: C[b,o] = IN - 2*popcount(xbits[b] ^ wbits[o]) + bias[o]
// 128x128 tile / block of 256 threads; 8x8 outputs per thread.
// K staged in LDS in 32-word chunks. uint4 groups are rotated by (row>>3)
// so compute-phase reads (rows strided by 8 across tx/ty) land on distinct
// bank groups (2-way max, which is free on CDNA4).
// Also emits per-column sum / sum-of-squares partials for the BatchNorm.
// ---------------------------------------------------------------------------
__global__ __launch_bounds__(256) void bin_gemm(
    const uint32_t* __restrict__ xb,   // [B_ROWS][KWORDS]
    const uint32_t* __restrict__ wb,   // [OUT_DIM][KWORDS]
    const float* __restrict__ bias,
    float* __restrict__ out,           // [B_ROWS][OUT_DIM]
    float* __restrict__ colsum,
    float* __restrict__ colsumsq)
{
    __shared__ uint4 a_lds[TILE * KC4];   // 16 KB
    __shared__ uint4 w_lds[TILE * KC4];   // 16 KB
    __shared__ float s_sum[TILE];
    __shared__ float s_sq[TILE];

    const int t  = threadIdx.x;
    const int tx = t & 15;
    const int ty = t >> 4;
    const int col0 = blockIdx.x * TILE;
    const int row0 = blockIdx.y * TILE;

    int acc[8][8];
#pragma unroll
    for (int i = 0; i < 8; ++i)
#pragma unroll
        for (int j = 0; j < 8; ++j) acc[i][j] = 0;

    const uint4* xg = reinterpret_cast<const uint4*>(xb);
    const uint4* wg = reinterpret_cast<const uint4*>(wb);

    for (int ch = 0; ch < NCHUNK; ++ch) {
        __syncthreads();
#pragma unroll
        for (int r = 0; r < 4; ++r) {
            int u   = r * 256 + t;
            int row = u >> 3;
            int g   = u & 7;
            int sw  = (g + (row >> 3)) & 7;              // bank-group rotate
            a_lds[row * KC4 + sw] = xg[(size_t)(row0 + row) * KW4 + ch * KC4 + g];
            w_lds[row * KC4 + sw] = wg[(size_t)(col0 + row) * KW4 + ch * KC4 + g];
        }
        __syncthreads();

        for (int k4 = 0; k4 < KC4; ++k4) {
            uint4 af[8], wf[8];
#pragma unroll
            for (int i = 0; i < 8; ++i)
                af[i] = a_lds[(ty * 8 + i) * KC4 + ((k4 + ty) & 7)];
#pragma unroll
            for (int j = 0; j < 8; ++j)
                wf[j] = w_lds[(tx * 8 + j) * KC4 + ((k4 + tx) & 7)];
#pragma unroll
            for (int i = 0; i < 8; ++i)
#pragma unroll
                for (int j = 0; j < 8; ++j) {
                    acc[i][j] += __popc(af[i].x ^ wf[j].x);
                    acc[i][j] += __popc(af[i].y ^ wf[j].y);
                    acc[i][j] += __popc(af[i].z ^ wf[j].z);
                    acc[i][j] += __popc(af[i].w ^ wf[j].w);
                }
        }
    }

    // ---- epilogue: value = IN - 2*pop + bias; write C; accumulate stats ----
    const float4* bias4 = reinterpret_cast<const float4*>(bias);
    float4 blo = bias4[(col0 + tx * 8) / 4 + 0];
    float4 bhi = bias4[(col0 + tx * 8) / 4 + 1];
    float bj[8] = {blo.x, blo.y, blo.z, blo.w, bhi.x, bhi.y, bhi.z, bhi.w};

    float csum[8], csq[8];
#pragma unroll
    for (int j = 0; j < 8; ++j) { csum[j] = 0.f; csq[j] = 0.f; }

#pragma unroll
    for (int i = 0; i < 8; ++i) {
        float vals[8];
#pragma unroll
        for (int j = 0; j < 8; ++j) {
            float v = (float)(IN_DIM - 2 * acc[i][j]) + bj[j];
            vals[j] = v;
            csum[j] += v;
            csq[j]  += v * v;
        }
        float4* op = reinterpret_cast<float4*>(
            &out[(size_t)(row0 + ty * 8 + i) * OUT_DIM + col0 + tx * 8]);
        op[0] = make_float4(vals[0], vals[1], vals[2], vals[3]);
        op[1] = make_float4(vals[4], vals[5], vals[6], vals[7]);
    }

    if (t < TILE) { s_sum[t] = 0.f; s_sq[t] = 0.f; }
    __syncthreads();
#pragma unroll
    for (int j = 0; j < 8; ++j) {
        atomicAdd(&s_sum[tx * 8 + j], csum[j]);
        atomicAdd(&s_sq[tx * 8 + j],  csq[j]);
    }
    __syncthreads();
    if (t < TILE) {
        atomicAdd(&colsum[col0 + t],   s_sum[t]);
        atomicAdd(&colsumsq[col0 + t], s_sq[t]);
    }
}

// ---------------------------------------------------------------------------
__global__ void bn_stats(const float* __restrict__ colsum,
                         const float* __restrict__ colsumsq,
                         float* __restrict__ mean, float* __restrict__ rstd) {
    int o = blockIdx.x * blockDim.x + threadIdx.x;
    float m = colsum[o] * (1.0f / B_ROWS);
    float v = colsumsq[o] * (1.0f / B_ROWS) - m * m;
    mean[o] = m;
    rstd[o] = rsqrtf(v + BN_EPS);
}

__global__ void bn_apply(float* __restrict__ out,
                         const float* __restrict__ mean,
                         const float* __restrict__ rstd) {
    size_t f = (size_t)blockIdx.x * blockDim.x + threadIdx.x;  // float4 index
    int c4 = (int)(f & (OUT_DIM / 4 - 1));
    float4 v = reinterpret_cast<float4*>(out)[f];
    float4 m = reinterpret_cast<const float4*>(mean)[c4];
    float4 r = reinterpret_cast<const float4*>(rstd)[c4];
    v.x = (v.x - m.x) * r.x;
    v.y = (v.y - m.y) * r.y;
    v.z = (v.z - m.z) * r.z;
    v.w = (v.w - m.w) * r.w;
    reinterpret_cast<float4*>(out)[f] = v;
}

// ---------------------------------------------------------------------------
extern "C" void kernel_launch(void* const* d_in, const int* in_sizes, int n_in,
                              void* d_out, int out_size, void* d_ws, size_t ws_size,
                              hipStream_t stream) {
    const float* x    = (const float*)d_in[0];
    const float* w    = (const float*)d_in[1];
    const float* bias = (const float*)d_in[2];
    float* out = (float*)d_out;

    uint8_t* ws = (uint8_t*)d_ws;
    uint32_t* xbits = (uint32_t*)ws;                                   // 4 MB
    uint32_t* wbits = (uint32_t*)(ws + (size_t)B_ROWS * KWORDS * 4);   // 2 MB
    float* colsum   = (float*)(ws + (size_t)B_ROWS * KWORDS * 4
                                  + (size_t)OUT_DIM * KWORDS * 4);
    float* colsumsq = colsum + OUT_DIM;
    float* mean     = colsumsq + OUT_DIM;
    float* rstd     = mean + OUT_DIM;

    hipMemsetAsync(colsum, 0, 2 * OUT_DIM * sizeof(float), stream);

    pack_signs<<<(B_ROWS * (IN_DIM / 4)) / 256, 256, 0, stream>>>(x, xbits);
    pack_signs<<<(OUT_DIM * (IN_DIM / 4)) / 256, 256, 0, stream>>>(w, wbits);

    bin_gemm<<<dim3(OUT_DIM / TILE, B_ROWS / TILE), 256, 0, stream>>>(
        xbits, wbits, bias, out, colsum, colsumsq);

    bn_stats<<<OUT_DIM / 256, 256, 0, stream>>>(colsum, colsumsq, mean, rstd);

    bn_apply<<<(unsigned)((size_t)B_ROWS * OUT_DIM / 4 / 256), 256, 0, stream>>>(
        out, mean, rstd);
}

// Round 2
// 448.234 us; speedup vs baseline: 2.0242x; 2.0242x over previous
//
#include <hip/hip_runtime.h>
#include <stdint.h>

#define B_ROWS 8192
#define IN_DIM 4096
#define OUT_DIM 4096
#define BN_EPS 1e-5f

#define TILE 128
#define BK 64                       // i8 k-elements per chunk (64 bytes/row)
#define NKCH (IN_DIM / BK)          // 64 K-iterations

typedef __attribute__((ext_vector_type(4))) int i32x4;

// ---------------------------------------------------------------------------
// fp32 -> int8 sign pack: {-1, 0, +1}. Exact (no sign(0) approximation).
// One thread = 4 floats -> one packed 4-byte word. Coalesced both sides.
// ---------------------------------------------------------------------------
__device__ __forceinline__ int sign_byte(float f) {
    int s = (f > 0.f) ? 1 : ((f < 0.f) ? -1 : 0);
    return s & 0xFF;
}

__global__ void pack_i8(const float* __restrict__ in, int* __restrict__ out) {
    int gid = blockIdx.x * blockDim.x + threadIdx.x;     // float4 index
    float4 v = reinterpret_cast<const float4*>(in)[gid];
    out[gid] = sign_byte(v.x) | (sign_byte(v.y) << 8) |
               (sign_byte(v.z) << 16) | (sign_byte(v.w) << 24);
}

// ---------------------------------------------------------------------------
// i8 MFMA GEMM (m97 structure): C[b,o] = sum_k A[b,k]*W[o,k], exact in i32.
// 128x128 tile / 256 threads (4 waves, 2x2); each wave: 4x4 grid of
// 16x16x64 i8 MFMAs. Staging via global_load_lds width=16. LDS rows are
// 64 B; the 16-B k-group index is XOR-swizzled by (row>>1)&3 so every
// 8-lane phase of a ds_read_b128 hits 32 distinct banks (2-way max = free).
// Swizzle is applied on the staging *global* address (global_load_lds's LDS
// destination is structurally lane*16-contiguous and cannot be swizzled).
// Epilogue writes fp32 C and accumulates per-column sum / sumsq for BN.
// Bias is omitted: it cancels exactly in (out - mean).
// ---------------------------------------------------------------------------
__global__ __launch_bounds__(256) void bin_gemm_i8(
    const int8_t* __restrict__ A,    // [B_ROWS][IN_DIM] i8
    const int8_t* __restrict__ W,    // [OUT_DIM][IN_DIM] i8
    float* __restrict__ out,         // [B_ROWS][OUT_DIM] f32 (raw dot)
    float* __restrict__ colsum,
    float* __restrict__ colsumsq)
{
    __shared__ i32x4 a_sm4[TILE * BK / 16];   // 8 KB
    __shared__ i32x4 b_sm4[TILE * BK / 16];   // 8 KB
    __shared__ float s_sum[TILE];
    __shared__ float s_sq[TILE];

    int8_t* a_sm = reinterpret_cast<int8_t*>(a_sm4);
    int8_t* b_sm = reinterpret_cast<int8_t*>(b_sm4);

    const int t      = threadIdx.x;
    const int lane   = t & 63;
    const int wave   = t >> 6;
    const int wr     = wave >> 1;          // wave row (0..1)
    const int wc     = wave & 1;           // wave col (0..1)
    const int lane16 = lane & 15;
    const int quad   = lane >> 4;
    const int row0   = blockIdx.y * TILE;
    const int col0   = blockIdx.x * TILE;

    if (t < TILE) { s_sum[t] = 0.f; s_sq[t] = 0.f; }

    i32x4 acc[4][4] = {};

    // staging role: waves 0,1 -> A halves; waves 2,3 -> B halves
    const int8_t* src  = (wave < 2) ? A : W;
    const int     gbase = (wave < 2) ? row0 : col0;
    int8_t*       dst  = (wave < 2) ? a_sm : b_sm;
    const int     half = (wave & 1) * 64;
    const int     lrow = lane >> 2;        // 0..15 within a 16-row stripe
    const int     slot = lane & 3;         // 16-B slot within the 64-B row

    for (int ch = 0; ch < NKCH; ++ch) {
        const int k0 = ch * BK;
        __syncthreads();                   // previous compute done
#pragma unroll
        for (int p = 0; p < 4; ++p) {
            int row = half + p * 16 + lrow;                    // tile row
            int g   = slot ^ ((row >> 1) & 3);                 // bank swizzle
            const int8_t* gp = src + (size_t)(gbase + row) * IN_DIM + k0 + g * 16;
            int8_t* lp = dst + (half + p * 16) * BK + lane * 16;
            __builtin_amdgcn_global_load_lds(
                (const __attribute__((address_space(1))) void*)gp,
                (__attribute__((address_space(3))) void*)lp, 16, 0, 0);
        }
        __syncthreads();                   // staging complete

        i32x4 af[4], bf[4];
#pragma unroll
        for (int i = 0; i < 4; ++i) {
            int row = wr * 64 + i * 16 + lane16;
            int s   = quad ^ ((row >> 1) & 3);
            af[i] = *reinterpret_cast<const i32x4*>(a_sm + row * BK + s * 16);
        }
#pragma unroll
        for (int j = 0; j < 4; ++j) {
            int col = wc * 64 + j * 16 + lane16;
            int s   = quad ^ ((col >> 1) & 3);
            bf[j] = *reinterpret_cast<const i32x4*>(b_sm + col * BK + s * 16);
        }
#pragma unroll
        for (int i = 0; i < 4; ++i)
#pragma unroll
            for (int j = 0; j < 4; ++j)
                acc[i][j] = __builtin_amdgcn_mfma_i32_16x16x64_i8(
                    af[i], bf[j], acc[i][j], 0, 0, 0);
    }

    // ---- epilogue: write fp32 C, accumulate per-column BN partials ----
    float csum[4] = {0.f, 0.f, 0.f, 0.f};
    float csq[4]  = {0.f, 0.f, 0.f, 0.f};
#pragma unroll
    for (int i = 0; i < 4; ++i) {
#pragma unroll
        for (int r = 0; r < 4; ++r) {
            int grow = row0 + wr * 64 + i * 16 + quad * 4 + r;  // C/D: row=quad*4+reg
            float* orow = out + (size_t)grow * OUT_DIM + col0 + wc * 64 + lane16;
#pragma unroll
            for (int j = 0; j < 4; ++j) {
                float v = (float)acc[i][j][r];
                orow[j * 16] = v;
                csum[j] += v;
                csq[j]  += v * v;
            }
        }
    }
    // reduce across the 4 quads (rows) of the wave: lanes L, L^16, L^32, L^48
#pragma unroll
    for (int j = 0; j < 4; ++j) {
        csum[j] += __shfl_xor(csum[j], 16);
        csum[j] += __shfl_xor(csum[j], 32);
        csq[j]  += __shfl_xor(csq[j], 16);
        csq[j]  += __shfl_xor(csq[j], 32);
    }
    if (quad == 0) {
#pragma unroll
        for (int j = 0; j < 4; ++j) {
            atomicAdd(&s_sum[wc * 64 + j * 16 + lane16], csum[j]);
            atomicAdd(&s_sq [wc * 64 + j * 16 + lane16], csq[j]);
        }
    }
    __syncthreads();
    if (t < TILE) {
        atomicAdd(&colsum[col0 + t],   s_sum[t]);
        atomicAdd(&colsumsq[col0 + t], s_sq[t]);
    }
}

// ---------------------------------------------------------------------------
__global__ void bn_stats(const float* __restrict__ colsum,
                         const float* __restrict__ colsumsq,
                         float* __restrict__ mean, float* __restrict__ rstd) {
    int o = blockIdx.x * blockDim.x + threadIdx.x;
    float m = colsum[o] * (1.0f / B_ROWS);
    float v = colsumsq[o] * (1.0f / B_ROWS) - m * m;
    mean[o] = m;
    rstd[o] = rsqrtf(v + BN_EPS);
}

__global__ void bn_apply(float* __restrict__ out,
                         const float* __restrict__ mean,
                         const float* __restrict__ rstd) {
    size_t f = (size_t)blockIdx.x * blockDim.x + threadIdx.x;  // float4 index
    int c4 = (int)(f & (OUT_DIM / 4 - 1));
    float4 v = reinterpret_cast<float4*>(out)[f];
    float4 m = reinterpret_cast<const float4*>(mean)[c4];
    float4 r = reinterpret_cast<const float4*>(rstd)[c4];
    v.x = (v.x - m.x) * r.x;
    v.y = (v.y - m.y) * r.y;
    v.z = (v.z - m.z) * r.z;
    v.w = (v.w - m.w) * r.w;
    reinterpret_cast<float4*>(out)[f] = v;
}

// ---------------------------------------------------------------------------
extern "C" void kernel_launch(void* const* d_in, const int* in_sizes, int n_in,
                              void* d_out, int out_size, void* d_ws, size_t ws_size,
                              hipStream_t stream) {
    const float* x = (const float*)d_in[0];
    const float* w = (const float*)d_in[1];
    float* out = (float*)d_out;

    uint8_t* ws = (uint8_t*)d_ws;
    int8_t* xb = (int8_t*)ws;                                      // 33.55 MB
    int8_t* wb = (int8_t*)(ws + (size_t)B_ROWS * IN_DIM);          // 16.78 MB
    float* colsum   = (float*)(ws + (size_t)B_ROWS * IN_DIM
                                  + (size_t)OUT_DIM * IN_DIM);
    float* colsumsq = colsum + OUT_DIM;
    float* mean     = colsumsq + OUT_DIM;
    float* rstd     = mean + OUT_DIM;

    hipMemsetAsync(colsum, 0, 2 * OUT_DIM * sizeof(float), stream);

    pack_i8<<<(B_ROWS * IN_DIM / 4) / 256, 256, 0, stream>>>(x, (int*)xb);
    pack_i8<<<(OUT_DIM * IN_DIM / 4) / 256, 256, 0, stream>>>(w, (int*)wb);

    bin_gemm_i8<<<dim3(OUT_DIM / TILE, B_ROWS / TILE), 256, 0, stream>>>(
        xb, wb, out, colsum, colsumsq);

    bn_stats<<<OUT_DIM / 256, 256, 0, stream>>>(colsum, colsumsq, mean, rstd);

    bn_apply<<<(unsigned)((size_t)B_ROWS * OUT_DIM / 4 / 256), 256, 0, stream>>>(
        out, mean, rstd);
}